// Round 8
// baseline (130.939 us; speedup 1.0000x reference)
//
#include <hip/hip_runtime.h>

#define B_ 16
#define C_ 512
#define N_ 1024

typedef __attribute__((ext_vector_type(8))) short bf16x8_t;
typedef __attribute__((ext_vector_type(4))) float f32x4_t;

__device__ __forceinline__ unsigned short f2bf(float f) {
  unsigned int u = __float_as_uint(f);
  u += 0x7fffu + ((u >> 16) & 1u);
  return (unsigned short)(u >> 16);
}

__device__ __forceinline__ f32x4_t mfma16(bf16x8_t a, bf16x8_t b, f32x4_t c) {
  return __builtin_amdgcn_mfma_f32_16x16x32_bf16(a, b, c, 0, 0, 0);
}

// async global->LDS, 16B per lane; dest must be wave-uniform base (lane*16 added by HW)
__device__ __forceinline__ void gload_lds16(const void* g, void* l) {
  __builtin_amdgcn_global_load_lds(
      (const __attribute__((address_space(1))) unsigned int*)g,
      (__attribute__((address_space(3))) unsigned int*)l, 16, 0, 0);
}

// ---------------------------------------------------------------- weights cast
// Stacks Wq|Wk|Wv into one (1536x512) bf16 buffer for the fused qkv GEMM.
__global__ __launch_bounds__(256) void castw_k(
    const float* __restrict__ qw, const float* __restrict__ kw,
    const float* __restrict__ vw, const float* __restrict__ pw,
    unsigned short* __restrict__ Wqkv, unsigned short* __restrict__ Wp) {
  int i = blockIdx.x * 256 + threadIdx.x;  // 262144 elements each
  Wqkv[i] = f2bf(qw[i]);
  Wqkv[262144 + i] = f2bf(kw[i]);
  Wqkv[524288 + i] = f2bf(vw[i]);
  Wp[i] = f2bf(pw[i]);
}

// ---------------------------------------------------------------- GN stats
__global__ __launch_bounds__(256) void gnstats_k(
    const float* __restrict__ x, float2* __restrict__ mv) {
  int b = blockIdx.x >> 5, g = blockIdx.x & 31;
  int t = threadIdx.x;
  const float* xg = x + ((long)b * C_ + g * 16) * N_;
  float s = 0.f, s2 = 0.f;
  for (int i = t; i < 4096; i += 256) {
    float4 v = ((const float4*)xg)[i];
    s += v.x + v.y + v.z + v.w;
    s2 += v.x * v.x + v.y * v.y + v.z * v.z + v.w * v.w;
  }
#pragma unroll
  for (int m = 1; m < 64; m <<= 1) {
    s += __shfl_xor(s, m);
    s2 += __shfl_xor(s2, m);
  }
  __shared__ float rs[4], rs2[4];
  int wave = t >> 6;
  if ((t & 63) == 0) { rs[wave] = s; rs2[wave] = s2; }
  __syncthreads();
  if (t == 0) {
    s = rs[0] + rs[1] + rs[2] + rs[3];
    s2 = rs2[0] + rs2[1] + rs2[2] + rs2[3];
    float mean = s * (1.f / 16384.f);
    float rv = rsqrtf(s2 * (1.f / 16384.f) - mean * mean + 1e-5f);
    mv[b * 32 + g] = make_float2(mean, rv);
  }
}

// ---------------------------------------------------------------- GN normalize
// Full-64B-line transposed stores (no partial-line RMW).
__global__ __launch_bounds__(256) void gnnorm_k(
    const float* __restrict__ x, const float* __restrict__ gw,
    const float* __restrict__ gb, const float2* __restrict__ mv,
    unsigned short* __restrict__ hn) {
  int f = blockIdx.x;
  int b = f >> 6, gp = (f >> 2) & 15, nc = f & 3;
  int t = threadIdx.x;
  int quad = t & 3, nrow = t >> 2;
  int h2 = quad >> 1;
  float2 m = mv[b * 32 + gp * 2 + h2];
  int c0 = quad * 8;
  float ga[8], be[8];
#pragma unroll
  for (int jj = 0; jj < 8; ++jj) {
    int gc = gp * 32 + c0 + jj;
    ga[jj] = gw[gc] * m.y;
    be[jj] = gb[gc] - m.x * ga[jj];
  }
  const float* xg = x + ((long)b * C_ + gp * 32) * N_;
  unsigned short* ob = hn + (long)b * N_ * C_ + gp * 32 + c0;
  for (int j = 0; j < 4; ++j) {
    int n = nc * 256 + j * 64 + nrow;
    unsigned short us[8];
#pragma unroll
    for (int jj = 0; jj < 8; ++jj)
      us[jj] = f2bf(xg[(long)(c0 + jj) * N_ + n] * ga[jj] + be[jj]);
    *(uint4*)(ob + (long)n * C_) = *(uint4*)us;
  }
}

// ---------------------------------------------------------------- QKV GEMM
// A = stacked Wqkv (1536x512), B = HN (b,n,c). 128x128 tile, BK=64, gload_lds
// staging with source-side XOR permute. Epilogue per 512-row slab:
//  slab 0 -> Q2 frag-blocked [n/16][c/8][n%16][c%8], *scale
//  slab 1 -> K2 same layout
//  slab 2 -> V2 frag-blocked [c/16][n/8][c%16][n%8] (transposed roles for PV)
__global__ __launch_bounds__(256) void gemm_qkv(
    const unsigned short* __restrict__ W, const unsigned short* __restrict__ HN,
    const float* __restrict__ qb, const float* __restrict__ kb,
    const float* __restrict__ vb, unsigned short* __restrict__ Q2,
    unsigned short* __restrict__ K2, unsigned short* __restrict__ V2,
    float scale) {
  int bz = blockIdx.z;
  const unsigned short* Ab = W + (long)blockIdx.x * 128 * 512;
  const unsigned short* Bb =
      HN + (long)bz * N_ * C_ + (long)blockIdx.y * 128 * 512;
  __shared__ char lds[32768];
  char* As = lds;
  char* Bs = lds + 16384;
  int tid = threadIdx.x;
  int lane = tid & 63, wave = tid >> 6;
  int wr = wave >> 1, wc = wave & 1;
  int lrow = lane & 15, kgrp = lane >> 4;
  f32x4_t acc[4][4];
#pragma unroll
  for (int i = 0; i < 4; ++i)
#pragma unroll
    for (int j = 0; j < 4; ++j) acc[i][j] = (f32x4_t){0.f, 0.f, 0.f, 0.f};

  int perm = (((lane & 7) ^ (lane >> 3)) << 3);
  const unsigned short* Asrc = Ab + (long)(wave * 32 + (lane >> 3)) * 512 + perm;
  const unsigned short* Bsrc = Bb + (long)(wave * 32 + (lane >> 3)) * 512 + perm;
  char* Adst = As + wave * 32 * 128;
  char* Bdst = Bs + wave * 32 * 128;

  for (int kt = 0; kt < 8; ++kt) {
    __syncthreads();
#pragma unroll
    for (int i = 0; i < 4; ++i) {
      gload_lds16(Asrc + (long)i * 8 * 512 + kt * 64, Adst + i * 1024);
      gload_lds16(Bsrc + (long)i * 8 * 512 + kt * 64, Bdst + i * 1024);
    }
    __syncthreads();
#pragma unroll
    for (int ks = 0; ks < 2; ++ks) {
      bf16x8_t af[4], bfv[4];
#pragma unroll
      for (int mi = 0; mi < 4; ++mi) {
        int r = wr * 64 + mi * 16 + lrow;
        int o = r * 128 + ks * 64 + kgrp * 16;
        o ^= (r & 7) << 4;
        af[mi] = *(bf16x8_t*)(As + o);
      }
#pragma unroll
      for (int ni = 0; ni < 4; ++ni) {
        int r = wc * 64 + ni * 16 + lrow;
        int o = r * 128 + ks * 64 + kgrp * 16;
        o ^= (r & 7) << 4;
        bfv[ni] = *(bf16x8_t*)(Bs + o);
      }
#pragma unroll
      for (int mi = 0; mi < 4; ++mi)
#pragma unroll
        for (int ni = 0; ni < 4; ++ni)
          acc[mi][ni] = mfma16(af[mi], bfv[ni], acc[mi][ni]);
    }
  }

  int slab = blockIdx.x >> 2;
  const float* bias = slab == 0 ? qb : (slab == 1 ? kb : vb);
  float scl = slab == 0 ? scale : 1.f;
  int rowloc = (blockIdx.x & 3) * 128 + wr * 64;  // c within slab
  int colbase = blockIdx.y * 128 + wc * 64;       // n
  unsigned short* ob =
      (slab == 0 ? Q2 : (slab == 1 ? K2 : V2)) + ((long)bz << 19);
#pragma unroll
  for (int mi = 0; mi < 4; ++mi) {
#pragma unroll
    for (int ni = 0; ni < 4; ++ni) {
      int row0 = rowloc + mi * 16 + kgrp * 4;
      int col = colbase + ni * 16 + lrow;
      unsigned short us[4];
#pragma unroll
      for (int rg = 0; rg < 4; ++rg)
        us[rg] = f2bf((acc[mi][ni][rg] + bias[row0 + rg]) * scl);
      if (slab < 2) {
        long off = ((long)(col >> 4) << 13) + ((long)(row0 >> 3) << 7) +
                   ((col & 15) << 3) + (row0 & 7);
        *(ushort4*)(ob + off) = make_ushort4(us[0], us[1], us[2], us[3]);
      } else {
        long base16 = ((long)(row0 >> 4) << 14) + ((long)(col >> 3) << 7) +
                      (col & 7) + (row0 & 15) * 8;
#pragma unroll
        for (int rg = 0; rg < 4; ++rg) ob[base16 + rg * 8] = us[rg];
      }
    }
  }
}

// ---------------------------------------------------------------- fused attn+PV
// 256 blocks x 512 threads (8 waves); b = f&15 pins batch to XCD b%8; exactly
// 1 block/CU. Per block: 64 q-rows. Phase 1: QK^T, wave owns 128 key cols;
// exact softmax (8-wave LDS reduce). Phase 2: P (64x1024 bf16 = 128KB) staged
// frag-blocked in LDS with chunk-XOR; wave computes a 64-channel O slice over
// all 1024 j from frag-blocked V2 (L2-resident). Halves per-batch K2/V2 L2
// re-reads vs 32-row blocks.
__global__ __launch_bounds__(512, 1) void attn_pv_k(
    const unsigned short* __restrict__ q2, const unsigned short* __restrict__ k2,
    const unsigned short* __restrict__ v2, unsigned short* __restrict__ ao) {
  int f = blockIdx.x;
  int b = f & 15, ib = f >> 4;  // rows ib*64..+64
  int tid = threadIdx.x, lane = tid & 63, wave = tid >> 6;  // 8 waves
  int lrow = lane & 15, kgrp = lane >> 4;
  __shared__ unsigned short P2[65536];  // [4 h][128 jb][16x8 frag] = 128KB
  __shared__ float red[2][8][64];
  f32x4_t acc[4][8];
#pragma unroll
  for (int h = 0; h < 4; ++h)
#pragma unroll
    for (int t = 0; t < 8; ++t) acc[h][t] = (f32x4_t){0.f, 0.f, 0.f, 0.f};
  const unsigned short* qb =
      q2 + ((long)b << 19) + ((long)(ib * 4) << 13) + lane * 8;
  const unsigned short* kb =
      k2 + ((long)b << 19) + ((long)(wave * 8) << 13) + lane * 8;
  for (int ks = 0; ks < 16; ++ks) {  // K = 512
    bf16x8_t qa[4];
#pragma unroll
    for (int h = 0; h < 4; ++h)
      qa[h] = *(const bf16x8_t*)(qb + h * 8192 + ks * 512);
    bf16x8_t kf[8];
#pragma unroll
    for (int t = 0; t < 8; ++t)
      kf[t] = *(const bf16x8_t*)(kb + t * 8192 + ks * 512);
#pragma unroll
    for (int h = 0; h < 4; ++h)
#pragma unroll
      for (int t = 0; t < 8; ++t) acc[h][t] = mfma16(qa[h], kf[t], acc[h][t]);
  }
  // ---- softmax (rows r = h*16 + kgrp*4 + rg; cols split across 8 waves) ----
  float mx[4][4];
#pragma unroll
  for (int h = 0; h < 4; ++h)
#pragma unroll
    for (int rg = 0; rg < 4; ++rg) mx[h][rg] = -1e30f;
#pragma unroll
  for (int h = 0; h < 4; ++h)
#pragma unroll
    for (int t = 0; t < 8; ++t)
#pragma unroll
      for (int rg = 0; rg < 4; ++rg) mx[h][rg] = fmaxf(mx[h][rg], acc[h][t][rg]);
#pragma unroll
  for (int m = 1; m < 16; m <<= 1)
#pragma unroll
    for (int h = 0; h < 4; ++h)
#pragma unroll
      for (int rg = 0; rg < 4; ++rg)
        mx[h][rg] = fmaxf(mx[h][rg], __shfl_xor(mx[h][rg], m));
  if (lrow == 0) {
#pragma unroll
    for (int h = 0; h < 4; ++h)
#pragma unroll
      for (int rg = 0; rg < 4; ++rg)
        red[0][wave][h * 16 + kgrp * 4 + rg] = mx[h][rg];
  }
  __syncthreads();
  float gm[4][4], sm[4][4];
#pragma unroll
  for (int h = 0; h < 4; ++h)
#pragma unroll
    for (int rg = 0; rg < 4; ++rg) {
      int r = h * 16 + kgrp * 4 + rg;
      float g0 = fmaxf(fmaxf(red[0][0][r], red[0][1][r]),
                       fmaxf(red[0][2][r], red[0][3][r]));
      float g1 = fmaxf(fmaxf(red[0][4][r], red[0][5][r]),
                       fmaxf(red[0][6][r], red[0][7][r]));
      gm[h][rg] = fmaxf(g0, g1);
      sm[h][rg] = 0.f;
    }
  // exp + stage P to LDS: off = h*16384 + jb*128 + (j&7) + ((row<<3)^cx)
#pragma unroll
  for (int h = 0; h < 4; ++h)
#pragma unroll
    for (int t = 0; t < 8; ++t) {
      int j = wave * 128 + t * 16 + lrow;
      int jb = j >> 3;
      int ob = h * 16384 + jb * 128 + (j & 7);
      int cx = (jb & 7) << 3;
#pragma unroll
      for (int rg = 0; rg < 4; ++rg) {
        float p = __expf(acc[h][t][rg] - gm[h][rg]);
        sm[h][rg] += p;
        P2[ob + (((kgrp * 4 + rg) << 3) ^ cx)] = f2bf(p);
      }
    }
#pragma unroll
  for (int m = 1; m < 16; m <<= 1)
#pragma unroll
    for (int h = 0; h < 4; ++h)
#pragma unroll
      for (int rg = 0; rg < 4; ++rg) sm[h][rg] += __shfl_xor(sm[h][rg], m);
  if (lrow == 0) {
#pragma unroll
    for (int h = 0; h < 4; ++h)
#pragma unroll
      for (int rg = 0; rg < 4; ++rg)
        red[1][wave][h * 16 + kgrp * 4 + rg] = sm[h][rg];
  }
  __syncthreads();
  float inv[4][4];
#pragma unroll
  for (int h = 0; h < 4; ++h)
#pragma unroll
    for (int rg = 0; rg < 4; ++rg) {
      int r = h * 16 + kgrp * 4 + rg;
      float s0 = red[1][0][r] + red[1][1][r] + red[1][2][r] + red[1][3][r];
      float s1 = red[1][4][r] + red[1][5][r] + red[1][6][r] + red[1][7][r];
      inv[h][rg] = 1.f / (s0 + s1);
    }
  // ---- PV: wave owns channels [wave*64, +64), j = all 1024 ----
  f32x4_t o[4][4];
#pragma unroll
  for (int h = 0; h < 4; ++h)
#pragma unroll
    for (int cf = 0; cf < 4; ++cf) o[h][cf] = (f32x4_t){0.f, 0.f, 0.f, 0.f};
  const unsigned short* vbp =
      v2 + ((long)b << 19) + ((long)(wave * 4) << 14) + lane * 8;
  for (int js = 0; js < 32; ++js) {
    int jb = js * 4 + kgrp;
    int pox = ((lrow ^ (jb & 7)) << 3) + jb * 128;
    bf16x8_t pa[4];
#pragma unroll
    for (int h = 0; h < 4; ++h)
      pa[h] = *(const bf16x8_t*)&P2[h * 16384 + pox];
    bf16x8_t vf[4];
#pragma unroll
    for (int cf = 0; cf < 4; ++cf)
      vf[cf] = *(const bf16x8_t*)(vbp + cf * 16384 + js * 512);
#pragma unroll
    for (int h = 0; h < 4; ++h)
#pragma unroll
      for (int cf = 0; cf < 4; ++cf)
        o[h][cf] = mfma16(pa[h], vf[cf], o[h][cf]);
  }
  unsigned short* aob = ao + ((long)(b * N_ + ib * 64)) * C_;
#pragma unroll
  for (int h = 0; h < 4; ++h)
#pragma unroll
    for (int cf = 0; cf < 4; ++cf) {
      int c = wave * 64 + cf * 16 + lrow;
#pragma unroll
      for (int rg = 0; rg < 4; ++rg) {
        int i = h * 16 + kgrp * 4 + rg;
        aob[(long)i * C_ + c] = f2bf(o[h][cf][rg] * inv[h][rg]);
      }
    }
}

// ---------------------------------------------------------------- proj GEMM
// out = x + Wp*AO^T + pb (fp32, (b,c,n)); A=Wp (512x512), B=AO (b,n,c).
__global__ __launch_bounds__(256) void gemm_proj(
    const unsigned short* __restrict__ A, const unsigned short* __restrict__ Bm,
    const float* __restrict__ bias, const float* __restrict__ resid,
    float* __restrict__ outp) {
  int bz = blockIdx.z;
  const unsigned short* Ab = A + (long)blockIdx.x * 128 * 512;
  const unsigned short* Bb =
      Bm + (long)bz * N_ * C_ + (long)blockIdx.y * 128 * 512;
  __shared__ char lds[32768];
  char* As = lds;
  char* Bs = lds + 16384;
  int tid = threadIdx.x;
  int lane = tid & 63, wave = tid >> 6;
  int wr = wave >> 1, wc = wave & 1;
  int lrow = lane & 15, kgrp = lane >> 4;
  f32x4_t acc[4][4];
#pragma unroll
  for (int i = 0; i < 4; ++i)
#pragma unroll
    for (int j = 0; j < 4; ++j) acc[i][j] = (f32x4_t){0.f, 0.f, 0.f, 0.f};

  int perm = (((lane & 7) ^ (lane >> 3)) << 3);
  const unsigned short* Asrc = Ab + (long)(wave * 32 + (lane >> 3)) * 512 + perm;
  const unsigned short* Bsrc = Bb + (long)(wave * 32 + (lane >> 3)) * 512 + perm;
  char* Adst = As + wave * 32 * 128;
  char* Bdst = Bs + wave * 32 * 128;

  for (int kt = 0; kt < 8; ++kt) {
    __syncthreads();
#pragma unroll
    for (int i = 0; i < 4; ++i) {
      gload_lds16(Asrc + (long)i * 8 * 512 + kt * 64, Adst + i * 1024);
      gload_lds16(Bsrc + (long)i * 8 * 512 + kt * 64, Bdst + i * 1024);
    }
    __syncthreads();
#pragma unroll
    for (int ks = 0; ks < 2; ++ks) {
      bf16x8_t af[4], bfv[4];
#pragma unroll
      for (int mi = 0; mi < 4; ++mi) {
        int r = wr * 64 + mi * 16 + lrow;
        int o = r * 128 + ks * 64 + kgrp * 16;
        o ^= (r & 7) << 4;
        af[mi] = *(bf16x8_t*)(As + o);
      }
#pragma unroll
      for (int ni = 0; ni < 4; ++ni) {
        int r = wc * 64 + ni * 16 + lrow;
        int o = r * 128 + ks * 64 + kgrp * 16;
        o ^= (r & 7) << 4;
        bfv[ni] = *(bf16x8_t*)(Bs + o);
      }
#pragma unroll
      for (int mi = 0; mi < 4; ++mi)
#pragma unroll
        for (int ni = 0; ni < 4; ++ni)
          acc[mi][ni] = mfma16(af[mi], bfv[ni], acc[mi][ni]);
    }
  }

  int rowbase = blockIdx.x * 128 + wr * 64;
  int colbase = blockIdx.y * 128 + wc * 64;
  float* ob = outp + (long)bz * C_ * N_;
  const float* rb = resid + (long)bz * C_ * N_;
#pragma unroll
  for (int mi = 0; mi < 4; ++mi) {
#pragma unroll
    for (int ni = 0; ni < 4; ++ni) {
      int row0 = rowbase + mi * 16 + kgrp * 4;
      int col = colbase + ni * 16 + lrow;
#pragma unroll
      for (int rg = 0; rg < 4; ++rg) {
        int r = row0 + rg;
        ob[(long)r * N_ + col] =
            acc[mi][ni][rg] + bias[r] + rb[(long)r * N_ + col];
      }
    }
  }
}

// ---------------------------------------------------------------- launch
extern "C" void kernel_launch(void* const* d_in, const int* in_sizes, int n_in,
                              void* d_out, int out_size, void* d_ws,
                              size_t ws_size, hipStream_t stream) {
  (void)in_sizes; (void)n_in; (void)out_size; (void)ws_size;
  const float* x = (const float*)d_in[0];
  const float* nw = (const float*)d_in[1];
  const float* nb = (const float*)d_in[2];
  const float* qw = (const float*)d_in[3];
  const float* qbias = (const float*)d_in[4];
  const float* kw = (const float*)d_in[5];
  const float* kbias = (const float*)d_in[6];
  const float* vw = (const float*)d_in[7];
  const float* vbias = (const float*)d_in[8];
  const float* pw = (const float*)d_in[9];
  const float* pbias = (const float*)d_in[10];
  float* out = (float*)d_out;

  char* ws = (char*)d_ws;
  unsigned short* WQKV = (unsigned short*)(ws + 0);        // 3MB stacked
  unsigned short* Wp = (unsigned short*)(ws + 1572864);    // 0.5MB
  unsigned short* HN = (unsigned short*)(ws + 2097152);    // 16MB (b,n,c)
  unsigned short* Q2 = (unsigned short*)(ws + 18874368);   // 16MB frag [n/16][c/8]
  unsigned short* K2 = (unsigned short*)(ws + 35651584);   // 16MB frag [n/16][c/8]
  unsigned short* V2 = (unsigned short*)(ws + 52428800);   // 16MB frag [c/16][n/8]
  unsigned short* AO = (unsigned short*)(ws + 69206016);   // 16MB (b,n,c)
  float2* MV = (float2*)(ws + 102760448);                  // 4KB (b,g) stats

  castw_k<<<1024, 256, 0, stream>>>(qw, kw, vw, pw, WQKV, Wp);
  gnstats_k<<<512, 256, 0, stream>>>(x, MV);
  gnnorm_k<<<1024, 256, 0, stream>>>(x, nw, nb, MV, HN);

  const float scale = 0.04419417382415922f;  // 512^-0.5
  // q,k,v in one dispatch
  gemm_qkv<<<dim3(12, 8, B_), 256, 0, stream>>>(WQKV, HN, qbias, kbias, vbias,
                                                Q2, K2, V2, scale);
  // fused QK^T + softmax + PV -> AO (b,n,c)
  attn_pv_k<<<256, 512, 0, stream>>>(Q2, K2, V2, AO);
  // out = x + Wp*AO^T + pb (fp32, (b,c,n))
  gemm_proj<<<dim3(4, 8, B_), 256, 0, stream>>>(Wp, AO, pbias, x, out);
}

// Round 9
// 112.940 us; speedup vs baseline: 1.1594x; 1.1594x over previous
//
#include <hip/hip_runtime.h>

#define B_ 16
#define C_ 512
#define N_ 1024

typedef __attribute__((ext_vector_type(8))) short bf16x8_t;
typedef __attribute__((ext_vector_type(4))) float f32x4_t;

__device__ __forceinline__ unsigned short f2bf(float f) {
  unsigned int u = __float_as_uint(f);
  u += 0x7fffu + ((u >> 16) & 1u);
  return (unsigned short)(u >> 16);
}

__device__ __forceinline__ f32x4_t mfma16(bf16x8_t a, bf16x8_t b, f32x4_t c) {
  return __builtin_amdgcn_mfma_f32_16x16x32_bf16(a, b, c, 0, 0, 0);
}

// async global->LDS, 16B per lane; dest is wave-uniform base (lane*16 added by HW)
__device__ __forceinline__ void gload_lds16(const void* g, void* l) {
  __builtin_amdgcn_global_load_lds(
      (const __attribute__((address_space(1))) unsigned int*)g,
      (__attribute__((address_space(3))) unsigned int*)l, 16, 0, 0);
}

// ---------------------------------------------------------------- weights cast
// Stacks Wq|Wk|Wv into one (1536x512) bf16 buffer for the fused qkv GEMM.
__global__ __launch_bounds__(256) void castw_k(
    const float* __restrict__ qw, const float* __restrict__ kw,
    const float* __restrict__ vw, const float* __restrict__ pw,
    unsigned short* __restrict__ Wqkv, unsigned short* __restrict__ Wp) {
  int i = blockIdx.x * 256 + threadIdx.x;  // 262144 elements each
  Wqkv[i] = f2bf(qw[i]);
  Wqkv[262144 + i] = f2bf(kw[i]);
  Wqkv[524288 + i] = f2bf(vw[i]);
  Wp[i] = f2bf(pw[i]);
}

// ---------------------------------------------------------------- fused GN
// Block per (b, pair-of-groups): 256 blocks x 512 threads. Reads the 32ch x
// 1024 fp32 slab ONCE (coalesced float4), keeps it in LDS (XOR-swizzled),
// reduces stats in-register, then normalizes from LDS with full-64B-line
// transposed stores to hn (b,n,c) bf16.
__global__ __launch_bounds__(512, 1) void gn_fused_k(
    const float* __restrict__ x, const float* __restrict__ gw,
    const float* __restrict__ gb, unsigned short* __restrict__ hn) {
  int blk = blockIdx.x;
  int b = blk >> 4, gp = blk & 15;
  int t = threadIdx.x, lane = t & 63, wave = t >> 6;
  __shared__ float xs[32768];      // [c][n ^ (((c>>3)&3)<<4)] = 128KB
  __shared__ float red[2][2][8];   // [sum/sq][group][wave]
  const float* xg = x + ((long)b * C_ + gp * 32) * N_;  // 128KB contiguous
  float s0 = 0.f, s20 = 0.f, s1 = 0.f, s21 = 0.f;
#pragma unroll
  for (int i = 0; i < 16; ++i) {
    int f4 = t + 512 * i;
    float4 v = ((const float4*)xg)[f4];
    float sum = v.x + v.y + v.z + v.w;
    float sq = v.x * v.x + v.y * v.y + v.z * v.z + v.w * v.w;
    if (i < 8) { s0 += sum; s20 += sq; } else { s1 += sum; s21 += sq; }
    int fi = f4 << 2;
    int c = fi >> 10, n = fi & 1023;
    int nx = n ^ (((c >> 3) & 3) << 4);
    *(float4*)&xs[(c << 10) + nx] = v;
  }
#pragma unroll
  for (int m = 1; m < 64; m <<= 1) {
    s0 += __shfl_xor(s0, m); s20 += __shfl_xor(s20, m);
    s1 += __shfl_xor(s1, m); s21 += __shfl_xor(s21, m);
  }
  if (lane == 0) {
    red[0][0][wave] = s0; red[1][0][wave] = s20;
    red[0][1][wave] = s1; red[1][1][wave] = s21;
  }
  __syncthreads();
  float m0 = 0.f, v0 = 0.f, m1 = 0.f, v1 = 0.f;
#pragma unroll
  for (int w = 0; w < 8; ++w) {
    m0 += red[0][0][w]; v0 += red[1][0][w];
    m1 += red[0][1][w]; v1 += red[1][1][w];
  }
  m0 *= (1.f / 16384.f); m1 *= (1.f / 16384.f);
  float rv0 = rsqrtf(v0 * (1.f / 16384.f) - m0 * m0 + 1e-5f);
  float rv1 = rsqrtf(v1 * (1.f / 16384.f) - m1 * m1 + 1e-5f);
  int q = t & 3;
  float mean = (q >> 1) ? m1 : m0, rv = (q >> 1) ? rv1 : rv0;
  float ga[8], be[8];
#pragma unroll
  for (int jj = 0; jj < 8; ++jj) {
    int gc = gp * 32 + q * 8 + jj;
    ga[jj] = gw[gc] * rv;
    be[jj] = gb[gc] - mean * ga[jj];
  }
  unsigned short* ob = hn + (long)b * N_ * C_ + gp * 32 + q * 8;
  int n0 = t >> 2;  // 0..127
  for (int it = 0; it < 8; ++it) {
    int n = n0 + (it << 7);
    int nsw = n ^ (q << 4);
    unsigned short us[8];
#pragma unroll
    for (int jj = 0; jj < 8; ++jj) {
      int c = q * 8 + jj;
      us[jj] = f2bf(xs[(c << 10) + nsw] * ga[jj] + be[jj]);
    }
    *(uint4*)(ob + (long)n * C_) = *(uint4*)us;
  }
}

// ---------------------------------------------------------------- QKV GEMM
// A = stacked Wqkv (1536x512), B = HN (b,n,c). 128x128 tile, BK=64, gload_lds
// staging with source-side XOR permute; bijective XCD swizzle clusters blocks
// sharing a B-panel onto one XCD L2. Epilogue per 512-row slab:
//  slab 0 -> Q2 frag-blocked [n/16][c/8][n%16][c%8], *scale
//  slab 1 -> K2 same layout
//  slab 2 -> V2 frag-blocked [c/16][n/8][c%16][n%8] (transposed roles for PV)
__global__ __launch_bounds__(256) void gemm_qkv(
    const unsigned short* __restrict__ W, const unsigned short* __restrict__ HN,
    const float* __restrict__ qb, const float* __restrict__ kb,
    const float* __restrict__ vb, unsigned short* __restrict__ Q2,
    unsigned short* __restrict__ K2, unsigned short* __restrict__ V2,
    float scale) {
  int flat = blockIdx.x + 12 * (blockIdx.y + 8 * blockIdx.z);  // 1536 = 8*192
  int nf = (flat & 7) * 192 + (flat >> 3);
  int bxi = nf % 12, rem = nf / 12;
  int byi = rem & 7, bz = rem >> 3;
  const unsigned short* Ab = W + (long)bxi * 128 * 512;
  const unsigned short* Bb = HN + (long)bz * N_ * C_ + (long)byi * 128 * 512;
  __shared__ char lds[32768];
  char* As = lds;
  char* Bs = lds + 16384;
  int tid = threadIdx.x;
  int lane = tid & 63, wave = tid >> 6;
  int wr = wave >> 1, wc = wave & 1;
  int lrow = lane & 15, kgrp = lane >> 4;
  f32x4_t acc[4][4];
#pragma unroll
  for (int i = 0; i < 4; ++i)
#pragma unroll
    for (int j = 0; j < 4; ++j) acc[i][j] = (f32x4_t){0.f, 0.f, 0.f, 0.f};

  int perm = (((lane & 7) ^ (lane >> 3)) << 3);
  const unsigned short* Asrc = Ab + (long)(wave * 32 + (lane >> 3)) * 512 + perm;
  const unsigned short* Bsrc = Bb + (long)(wave * 32 + (lane >> 3)) * 512 + perm;
  char* Adst = As + wave * 32 * 128;
  char* Bdst = Bs + wave * 32 * 128;

  for (int kt = 0; kt < 8; ++kt) {
    __syncthreads();
#pragma unroll
    for (int i = 0; i < 4; ++i) {
      gload_lds16(Asrc + (long)i * 8 * 512 + kt * 64, Adst + i * 1024);
      gload_lds16(Bsrc + (long)i * 8 * 512 + kt * 64, Bdst + i * 1024);
    }
    __syncthreads();
#pragma unroll
    for (int ks = 0; ks < 2; ++ks) {
      bf16x8_t af[4], bfv[4];
#pragma unroll
      for (int mi = 0; mi < 4; ++mi) {
        int r = wr * 64 + mi * 16 + lrow;
        int o = r * 128 + ks * 64 + kgrp * 16;
        o ^= (r & 7) << 4;
        af[mi] = *(bf16x8_t*)(As + o);
      }
#pragma unroll
      for (int ni = 0; ni < 4; ++ni) {
        int r = wc * 64 + ni * 16 + lrow;
        int o = r * 128 + ks * 64 + kgrp * 16;
        o ^= (r & 7) << 4;
        bfv[ni] = *(bf16x8_t*)(Bs + o);
      }
#pragma unroll
      for (int mi = 0; mi < 4; ++mi)
#pragma unroll
        for (int ni = 0; ni < 4; ++ni)
          acc[mi][ni] = mfma16(af[mi], bfv[ni], acc[mi][ni]);
    }
  }

  int slab = bxi >> 2;
  const float* bias = slab == 0 ? qb : (slab == 1 ? kb : vb);
  float scl = slab == 0 ? scale : 1.f;
  int rowloc = (bxi & 3) * 128 + wr * 64;  // c within slab
  int colbase = byi * 128 + wc * 64;       // n
  unsigned short* ob =
      (slab == 0 ? Q2 : (slab == 1 ? K2 : V2)) + ((long)bz << 19);
#pragma unroll
  for (int mi = 0; mi < 4; ++mi) {
#pragma unroll
    for (int ni = 0; ni < 4; ++ni) {
      int row0 = rowloc + mi * 16 + kgrp * 4;
      int col = colbase + ni * 16 + lrow;
      unsigned short us[4];
#pragma unroll
      for (int rg = 0; rg < 4; ++rg)
        us[rg] = f2bf((acc[mi][ni][rg] + bias[row0 + rg]) * scl);
      if (slab < 2) {
        long off = ((long)(col >> 4) << 13) + ((long)(row0 >> 3) << 7) +
                   ((col & 15) << 3) + (row0 & 7);
        *(ushort4*)(ob + off) = make_ushort4(us[0], us[1], us[2], us[3]);
      } else {
        long base16 = ((long)(row0 >> 4) << 14) + ((long)(col >> 3) << 7) +
                      (col & 7) + (row0 & 15) * 8;
#pragma unroll
        for (int rg = 0; rg < 4; ++rg) ob[base16 + rg * 8] = us[rg];
      }
    }
  }
}

// ---------------------------------------------------------------- fused attn+PV
// 256 blocks x 512 threads; b = f&15 pins batch to XCD b%8; 1 block/CU.
// Q (64KB) is LDS-staged into the P2 region (Q is dead before P is written,
// barrier-separated) -> kills 8x-redundant Q loads, qa moves to lgkm ds_read.
// Phase 1: QK^T (wave owns 128 key cols), exact softmax via 8-wave reduce.
// Phase 2: P staged frag-blocked w/ chunk-XOR; wave computes 64-channel O
// slice over all 1024 j from frag-blocked V2 (L2-resident). setprio around
// MFMA clusters (T5).
__global__ __launch_bounds__(512, 1) void attn_pv_k(
    const unsigned short* __restrict__ q2, const unsigned short* __restrict__ k2,
    const unsigned short* __restrict__ v2, unsigned short* __restrict__ ao) {
  int f = blockIdx.x;
  int b = f & 15, ib = f >> 4;  // rows ib*64..+64
  int tid = threadIdx.x, lane = tid & 63, wave = tid >> 6;  // 8 waves
  int lrow = lane & 15, kgrp = lane >> 4;
  __shared__ unsigned short P2[65536];  // 128KB; first 64KB doubles as Q stage
  __shared__ float red[2][8][64];
  // ---- stage Q: 64KB contiguous -> P2[0..32768) linear ----
  {
    const unsigned short* qsrc =
        q2 + ((long)b << 19) + ((long)(ib * 4) << 13) + wave * 4096 + lane * 8;
    char* qdst = (char*)P2 + wave * 8192;
#pragma unroll
    for (int i = 0; i < 8; ++i) gload_lds16(qsrc + i * 512, qdst + i * 1024);
  }
  asm volatile("s_waitcnt vmcnt(0)" ::: "memory");
  __syncthreads();
  f32x4_t acc[4][8];
#pragma unroll
  for (int h = 0; h < 4; ++h)
#pragma unroll
    for (int t = 0; t < 8; ++t) acc[h][t] = (f32x4_t){0.f, 0.f, 0.f, 0.f};
  const unsigned short* kb =
      k2 + ((long)b << 19) + ((long)(wave * 8) << 13) + lane * 8;
  for (int ks = 0; ks < 16; ++ks) {  // K = 512
    bf16x8_t kf[8];
#pragma unroll
    for (int t = 0; t < 8; ++t)
      kf[t] = *(const bf16x8_t*)(kb + t * 8192 + ks * 512);
    bf16x8_t qa[4];
#pragma unroll
    for (int h = 0; h < 4; ++h)
      qa[h] = *(const bf16x8_t*)&P2[h * 8192 + ks * 512 + lane * 8];
    __builtin_amdgcn_s_setprio(1);
#pragma unroll
    for (int h = 0; h < 4; ++h)
#pragma unroll
      for (int t = 0; t < 8; ++t) acc[h][t] = mfma16(qa[h], kf[t], acc[h][t]);
    __builtin_amdgcn_s_setprio(0);
  }
  // ---- softmax (rows r = h*16 + kgrp*4 + rg; cols split across 8 waves) ----
  float mx[4][4];
#pragma unroll
  for (int h = 0; h < 4; ++h)
#pragma unroll
    for (int rg = 0; rg < 4; ++rg) mx[h][rg] = -1e30f;
#pragma unroll
  for (int h = 0; h < 4; ++h)
#pragma unroll
    for (int t = 0; t < 8; ++t)
#pragma unroll
      for (int rg = 0; rg < 4; ++rg) mx[h][rg] = fmaxf(mx[h][rg], acc[h][t][rg]);
#pragma unroll
  for (int m = 1; m < 16; m <<= 1)
#pragma unroll
    for (int h = 0; h < 4; ++h)
#pragma unroll
      for (int rg = 0; rg < 4; ++rg)
        mx[h][rg] = fmaxf(mx[h][rg], __shfl_xor(mx[h][rg], m));
  if (lrow == 0) {
#pragma unroll
    for (int h = 0; h < 4; ++h)
#pragma unroll
      for (int rg = 0; rg < 4; ++rg)
        red[0][wave][h * 16 + kgrp * 4 + rg] = mx[h][rg];
  }
  __syncthreads();  // also separates Q reads from P writes below
  float gm[4][4], sm[4][4];
#pragma unroll
  for (int h = 0; h < 4; ++h)
#pragma unroll
    for (int rg = 0; rg < 4; ++rg) {
      int r = h * 16 + kgrp * 4 + rg;
      float g0 = fmaxf(fmaxf(red[0][0][r], red[0][1][r]),
                       fmaxf(red[0][2][r], red[0][3][r]));
      float g1 = fmaxf(fmaxf(red[0][4][r], red[0][5][r]),
                       fmaxf(red[0][6][r], red[0][7][r]));
      gm[h][rg] = fmaxf(g0, g1);
      sm[h][rg] = 0.f;
    }
  // exp + stage P to LDS: off = h*16384 + jb*128 + (j&7) + ((row<<3)^cx)
#pragma unroll
  for (int h = 0; h < 4; ++h)
#pragma unroll
    for (int t = 0; t < 8; ++t) {
      int j = wave * 128 + t * 16 + lrow;
      int jb = j >> 3;
      int ob = h * 16384 + jb * 128 + (j & 7);
      int cx = (jb & 7) << 3;
#pragma unroll
      for (int rg = 0; rg < 4; ++rg) {
        float p = __expf(acc[h][t][rg] - gm[h][rg]);
        sm[h][rg] += p;
        P2[ob + (((kgrp * 4 + rg) << 3) ^ cx)] = f2bf(p);
      }
    }
#pragma unroll
  for (int m = 1; m < 16; m <<= 1)
#pragma unroll
    for (int h = 0; h < 4; ++h)
#pragma unroll
      for (int rg = 0; rg < 4; ++rg) sm[h][rg] += __shfl_xor(sm[h][rg], m);
  if (lrow == 0) {
#pragma unroll
    for (int h = 0; h < 4; ++h)
#pragma unroll
      for (int rg = 0; rg < 4; ++rg)
        red[1][wave][h * 16 + kgrp * 4 + rg] = sm[h][rg];
  }
  __syncthreads();
  float inv[4][4];
#pragma unroll
  for (int h = 0; h < 4; ++h)
#pragma unroll
    for (int rg = 0; rg < 4; ++rg) {
      int r = h * 16 + kgrp * 4 + rg;
      float s0 = red[1][0][r] + red[1][1][r] + red[1][2][r] + red[1][3][r];
      float s1 = red[1][4][r] + red[1][5][r] + red[1][6][r] + red[1][7][r];
      inv[h][rg] = 1.f / (s0 + s1);
    }
  // ---- PV: wave owns channels [wave*64, +64), j = all 1024 ----
  f32x4_t o[4][4];
#pragma unroll
  for (int h = 0; h < 4; ++h)
#pragma unroll
    for (int cf = 0; cf < 4; ++cf) o[h][cf] = (f32x4_t){0.f, 0.f, 0.f, 0.f};
  const unsigned short* vbp =
      v2 + ((long)b << 19) + ((long)(wave * 4) << 14) + lane * 8;
  for (int js = 0; js < 32; ++js) {
    bf16x8_t vf[4];
#pragma unroll
    for (int cf = 0; cf < 4; ++cf)
      vf[cf] = *(const bf16x8_t*)(vbp + cf * 16384 + js * 512);
    int jb = js * 4 + kgrp;
    int pox = ((lrow ^ (jb & 7)) << 3) + jb * 128;
    bf16x8_t pa[4];
#pragma unroll
    for (int h = 0; h < 4; ++h)
      pa[h] = *(const bf16x8_t*)&P2[h * 16384 + pox];
    __builtin_amdgcn_s_setprio(1);
#pragma unroll
    for (int h = 0; h < 4; ++h)
#pragma unroll
      for (int cf = 0; cf < 4; ++cf)
        o[h][cf] = mfma16(pa[h], vf[cf], o[h][cf]);
    __builtin_amdgcn_s_setprio(0);
  }
  unsigned short* aob = ao + ((long)(b * N_ + ib * 64)) * C_;
#pragma unroll
  for (int h = 0; h < 4; ++h)
#pragma unroll
    for (int cf = 0; cf < 4; ++cf) {
      int c = wave * 64 + cf * 16 + lrow;
#pragma unroll
      for (int rg = 0; rg < 4; ++rg) {
        int i = h * 16 + kgrp * 4 + rg;
        aob[(long)i * C_ + c] = f2bf(o[h][cf][rg] * inv[h][rg]);
      }
    }
}

// ---------------------------------------------------------------- proj GEMM
// out = x + Wp*AO^T + pb (fp32, (b,c,n)); A=Wp (512x512), B=AO (b,n,c).
__global__ __launch_bounds__(256) void gemm_proj(
    const unsigned short* __restrict__ A, const unsigned short* __restrict__ Bm,
    const float* __restrict__ bias, const float* __restrict__ resid,
    float* __restrict__ outp) {
  int flat = blockIdx.x + 4 * (blockIdx.y + 8 * blockIdx.z);  // 512 = 8*64
  int nf = (flat & 7) * 64 + (flat >> 3);
  int bxi = nf & 3, byi = (nf >> 2) & 7, bz = nf >> 5;
  const unsigned short* Ab = A + (long)bxi * 128 * 512;
  const unsigned short* Bb = Bm + (long)bz * N_ * C_ + (long)byi * 128 * 512;
  __shared__ char lds[32768];
  char* As = lds;
  char* Bs = lds + 16384;
  int tid = threadIdx.x;
  int lane = tid & 63, wave = tid >> 6;
  int wr = wave >> 1, wc = wave & 1;
  int lrow = lane & 15, kgrp = lane >> 4;
  f32x4_t acc[4][4];
#pragma unroll
  for (int i = 0; i < 4; ++i)
#pragma unroll
    for (int j = 0; j < 4; ++j) acc[i][j] = (f32x4_t){0.f, 0.f, 0.f, 0.f};

  int perm = (((lane & 7) ^ (lane >> 3)) << 3);
  const unsigned short* Asrc = Ab + (long)(wave * 32 + (lane >> 3)) * 512 + perm;
  const unsigned short* Bsrc = Bb + (long)(wave * 32 + (lane >> 3)) * 512 + perm;
  char* Adst = As + wave * 32 * 128;
  char* Bdst = Bs + wave * 32 * 128;

  for (int kt = 0; kt < 8; ++kt) {
    __syncthreads();
#pragma unroll
    for (int i = 0; i < 4; ++i) {
      gload_lds16(Asrc + (long)i * 8 * 512 + kt * 64, Adst + i * 1024);
      gload_lds16(Bsrc + (long)i * 8 * 512 + kt * 64, Bdst + i * 1024);
    }
    __syncthreads();
#pragma unroll
    for (int ks = 0; ks < 2; ++ks) {
      bf16x8_t af[4], bfv[4];
#pragma unroll
      for (int mi = 0; mi < 4; ++mi) {
        int r = wr * 64 + mi * 16 + lrow;
        int o = r * 128 + ks * 64 + kgrp * 16;
        o ^= (r & 7) << 4;
        af[mi] = *(bf16x8_t*)(As + o);
      }
#pragma unroll
      for (int ni = 0; ni < 4; ++ni) {
        int r = wc * 64 + ni * 16 + lrow;
        int o = r * 128 + ks * 64 + kgrp * 16;
        o ^= (r & 7) << 4;
        bfv[ni] = *(bf16x8_t*)(Bs + o);
      }
#pragma unroll
      for (int mi = 0; mi < 4; ++mi)
#pragma unroll
        for (int ni = 0; ni < 4; ++ni)
          acc[mi][ni] = mfma16(af[mi], bfv[ni], acc[mi][ni]);
    }
  }

  int rowbase = bxi * 128 + wr * 64;
  int colbase = byi * 128 + wc * 64;
  float* ob = outp + (long)bz * C_ * N_;
  const float* rb = resid + (long)bz * C_ * N_;
#pragma unroll
  for (int mi = 0; mi < 4; ++mi) {
#pragma unroll
    for (int ni = 0; ni < 4; ++ni) {
      int row0 = rowbase + mi * 16 + kgrp * 4;
      int col = colbase + ni * 16 + lrow;
#pragma unroll
      for (int rg = 0; rg < 4; ++rg) {
        int r = row0 + rg;
        ob[(long)r * N_ + col] =
            acc[mi][ni][rg] + bias[r] + rb[(long)r * N_ + col];
      }
    }
  }
}

// ---------------------------------------------------------------- launch
extern "C" void kernel_launch(void* const* d_in, const int* in_sizes, int n_in,
                              void* d_out, int out_size, void* d_ws,
                              size_t ws_size, hipStream_t stream) {
  (void)in_sizes; (void)n_in; (void)out_size; (void)ws_size;
  const float* x = (const float*)d_in[0];
  const float* nw = (const float*)d_in[1];
  const float* nb = (const float*)d_in[2];
  const float* qw = (const float*)d_in[3];
  const float* qbias = (const float*)d_in[4];
  const float* kw = (const float*)d_in[5];
  const float* kbias = (const float*)d_in[6];
  const float* vw = (const float*)d_in[7];
  const float* vbias = (const float*)d_in[8];
  const float* pw = (const float*)d_in[9];
  const float* pbias = (const float*)d_in[10];
  float* out = (float*)d_out;

  char* ws = (char*)d_ws;
  unsigned short* WQKV = (unsigned short*)(ws + 0);        // 3MB stacked
  unsigned short* Wp = (unsigned short*)(ws + 1572864);    // 0.5MB
  unsigned short* HN = (unsigned short*)(ws + 2097152);    // 16MB (b,n,c)
  unsigned short* Q2 = (unsigned short*)(ws + 18874368);   // 16MB frag [n/16][c/8]
  unsigned short* K2 = (unsigned short*)(ws + 35651584);   // 16MB frag [n/16][c/8]
  unsigned short* V2 = (unsigned short*)(ws + 52428800);   // 16MB frag [c/16][n/8]
  unsigned short* AO = (unsigned short*)(ws + 69206016);   // 16MB (b,n,c)

  castw_k<<<1024, 256, 0, stream>>>(qw, kw, vw, pw, WQKV, Wp);
  gn_fused_k<<<256, 512, 0, stream>>>(x, nw, nb, HN);

  const float scale = 0.04419417382415922f;  // 512^-0.5
  // q,k,v in one dispatch
  gemm_qkv<<<dim3(12, 8, B_), 256, 0, stream>>>(WQKV, HN, qbias, kbias, vbias,
                                                Q2, K2, V2, scale);
  // fused QK^T + softmax + PV -> AO (b,n,c)
  attn_pv_k<<<256, 512, 0, stream>>>(Q2, K2, V2, AO);
  // out = x + Wp*AO^T + pb (fp32, (b,c,n))
  gemm_proj<<<dim3(4, 8, B_), 256, 0, stream>>>(Wp, AO, pbias, x, out);
}